// Round 17
// baseline (3533.482 us; speedup 1.0000x reference)
//
#include <hip/hip_runtime.h>
#include <hip/hip_bf16.h>

#define N_SRCN 200000
#define N_DSTN 50000
#define NEDGE 800000
#define KIN 256
#define NF 192        // H*OUT = 3*64
#define SLOPE 0.2f
#define NNT 13        // 12 feat col-tiles + 1 el/er projection tile
#define NITER 1563    // ceil(200000/128) 128-row iterations
#define GBLK 256      // persistent blocks

typedef __attribute__((ext_vector_type(8))) short bf16x8;
typedef __attribute__((ext_vector_type(4))) float f32x4;

__device__ __forceinline__ unsigned short f2bf(float f) {
    union { float f; unsigned int u; } v; v.f = f;
    unsigned int u = v.u;
    return (unsigned short)((u + 0x7FFFu + ((u >> 16) & 1u)) >> 16);  // RNE
}
__device__ __forceinline__ float bf2f(unsigned short h) {
    union { unsigned int u; float f; } v; v.u = ((unsigned int)h) << 16;
    return v.f;
}
__device__ __forceinline__ unsigned int cvt2(float lo, float hi) {
    __hip_bfloat162 h = __float22bfloat162_rn(float2{lo, hi});
    union { __hip_bfloat162 h; unsigned int u; } c; c.h = h;
    return c.u;
}
__device__ __forceinline__ void gl_lds16(const void* g, void* l) {
    __builtin_amdgcn_global_load_lds(
        (const __attribute__((address_space(1))) unsigned int*)g,
        (__attribute__((address_space(3))) unsigned int*)l, 16, 0, 0);
}

// ---------------- prep: pack W into 13-tile fragment-major Wp + row_ptr ------
// Wp[((ks*13 + nt)*64 + lane)*8 + j]:
//   nt<12 : bf16(W[nt*16 + (lane&15)][ks*32 + (lane>>4)*8 + j])
//   nt==12: projection tile (R12-verified): col cc=lane&15: cc<3 ->
//           (W^T attn_l)_cc, 3<=cc<6 -> (W^T attn_r)_{cc-3}, else 0.
__global__ void prep_kernel(const float* __restrict__ W,
                            const float* __restrict__ attn_l, const float* __restrict__ attn_r,
                            unsigned short* __restrict__ Wp,
                            const int* __restrict__ dst, int* __restrict__ rp) {
    const int bid = blockIdx.x;
    if (bid < 26) {
        int tid = bid * 256 + threadIdx.x;
        if (tid >= NNT * 8 * 64) return;
        int lane = tid & 63;
        int g = tid >> 6;
        int nt = g % NNT, ks = g / NNT;
        int k = ks * 32 + (lane >> 4) * 8;
        unsigned short* o = &Wp[tid * 8];
        if (nt < 12) {
            int col = nt * 16 + (lane & 15);
            const float* wsrc = &W[col * KIN + k];
            #pragma unroll
            for (int j = 0; j < 8; ++j) o[j] = f2bf(wsrc[j]);
        } else {
            int cc = lane & 15;
            #pragma unroll
            for (int j = 0; j < 8; ++j) {
                float s = 0.f;
                if (cc < 6) {
                    const int h = cc < 3 ? cc : cc - 3;
                    const float* aw = cc < 3 ? attn_l : attn_r;
                    for (int f = 0; f < 64; ++f)
                        s += aw[h * 64 + f] * W[(h * 64 + f) * KIN + k + j];
                }
                o[j] = f2bf(s);
            }
        }
    } else {
        int d = (bid - 26) * 256 + threadIdx.x;
        if (d > N_DSTN) return;
        int lo = 0, hi = NEDGE;
        while (lo < hi) {
            int mid = (lo + hi) >> 1;
            if (dst[mid] < d) lo = mid + 1; else hi = mid;
        }
        rp[d] = lo;
    }
}

// ---------------- GEMM: feat = x @ W^T (bf16 MFMA), el/er as GEMM columns ----
// 256 persistent blocks x 512 thr; Wp (104 KB, 13 tiles) in LDS once; no
// barriers in the loop. 8 waves = wr{0,1} x wc{0..3}. Per 128-row iteration,
// wave (wr,wc) computes 64 rows (4 row-tiles) x its col-tiles:
//   wc<3: nt {3wc,3wc+1,3wc+2}; wc3: nt {9,10,11,12(projection->el/er)}.
// Each ds_read_b128 B-fragment feeds FOUR MFMAs (4x amortization vs R11's 1).
// The 4 wc-waves read identical A rows temporally together -> same-XCD L2
// serves the re-reads; HBM x traffic stays ~1x (R16 lesson).
__global__ void __launch_bounds__(512, 1)
gemm_feat(const float* __restrict__ x, const unsigned short* __restrict__ Wp,
          unsigned short* __restrict__ feat,
          float* __restrict__ el4, float* __restrict__ er4) {
    __shared__ unsigned short Bl[NNT * 8 * 512];   // 104 KB
    const int t = threadIdx.x;
    const int wid = t >> 6, lane = t & 63;
    const int al = lane & 15, ah = lane >> 4;
    const int wr = wid >> 2, wc = wid & 3;
    const int nnt = wc < 3 ? 3 : 4;
    const int nt0 = wc * 3;                        // wc3 -> 9

    // ---- stage Wp -> LDS once (13 sweeps x 8KB) ----
    #pragma unroll
    for (int i = 0; i < 13; ++i) {
        const int off = (i * 8 + wid) * 1024;
        gl_lds16((const char*)Wp + off + lane * 16, (char*)Bl + off);
    }
    asm volatile("s_waitcnt vmcnt(0)" ::: "memory");
    __syncthreads();
    // ---- no barriers after this point ----

    for (int g = blockIdx.x; g < NITER; g += GBLK) {
        const int rbase = g * 128 + wr * 64;

        f32x4 acc[4][4] = {};                      // [rt][local nt]
        #pragma unroll
        for (int ks = 0; ks < 8; ++ks) {
            // B fragments for this ks (shared across the 4 row-tiles)
            bf16x8 bv[4];
            for (int q = 0; q < nnt; ++q)
                bv[q] = *(const bf16x8*)&Bl[(ks * NNT + nt0 + q) * 512 + lane * 8];
            #pragma unroll
            for (int rt = 0; rt < 4; ++rt) {
                const int row = rbase + rt * 16 + al;
                const int rs = row < N_SRCN ? row : N_SRCN - 1;   // tail clamp
                const float* xp = &x[(size_t)rs * KIN + ks * 32 + ah * 8];
                const float4 a0 = *(const float4*)xp;
                const float4 a1 = *(const float4*)(xp + 4);
                union { bf16x8 v; unsigned int u[4]; } av;
                av.u[0] = cvt2(a0.x, a0.y);
                av.u[1] = cvt2(a0.z, a0.w);
                av.u[2] = cvt2(a1.x, a1.y);
                av.u[3] = cvt2(a1.z, a1.w);
                for (int q = 0; q < nnt; ++q)
                    acc[rt][q] = __builtin_amdgcn_mfma_f32_16x16x32_bf16(av.v, bv[q], acc[rt][q], 0, 0, 0);
            }
        }

        // ---- feat stores (C/D: col=(nt0+q)*16+al, row=ah*4+e [m89]) ----
        #pragma unroll
        for (int rt = 0; rt < 4; ++rt) {
            #pragma unroll
            for (int e = 0; e < 4; ++e) {
                const int row = rbase + rt * 16 + ah * 4 + e;
                if (row < N_SRCN) {
                    for (int q = 0; q < (wc < 3 ? 3 : 3); ++q) {   // feat tiles only
                        const int col = (nt0 + q) * 16 + al;
                        feat[(size_t)row * NF + col] = f2bf(acc[rt][q][e]);
                    }
                }
            }
        }
        // ---- el/er from projection tile (wc3 only; acc[rt][3]) ----
        if (wc == 3) {
            #pragma unroll
            for (int rt = 0; rt < 4; ++rt) {
                #pragma unroll
                for (int e = 0; e < 4; ++e) {
                    const int row = rbase + rt * 16 + ah * 4 + e;
                    const float v = acc[rt][3][e];
                    if (row < N_SRCN) {
                        if (al < 3) el4[(size_t)row * 4 + al] = v;
                        else if (al < 6 && row < N_DSTN) er4[(size_t)row * 4 + (al - 3)] = v;
                    }
                }
            }
        }
    }
}

// ---------------- gather: edge softmax (no max shift) + weighted accumulate --
__launch_bounds__(256)
__global__ void gather_kernel(const unsigned short* __restrict__ feat,
                              const float* __restrict__ el4, const float* __restrict__ er4,
                              const int* __restrict__ src, const int* __restrict__ rp,
                              float* __restrict__ out) {
    const int lane = threadIdx.x & 63;
    const int d = (blockIdx.x * blockDim.x + threadIdx.x) >> 6;
    if (d >= N_DSTN) return;
    const int lo = rp[d], hi = rp[d + 1];
    const float4 erv = *(const float4*)&er4[(size_t)d * 4];

    float a0 = 0.f, a1 = 0.f, a2 = 0.f, s0 = 0.f, s1 = 0.f, s2 = 0.f;
    for (int base = lo; base < hi; base += 64) {
        const int cnt = min(64, hi - base);
        int sv = 0; float w0 = 0.f, w1 = 0.f, w2 = 0.f;
        if (lane < cnt) {
            sv = src[base + lane];
            const float4 elv = *(const float4*)&el4[(size_t)sv * 4];
            float e0 = elv.x + erv.x; e0 = e0 >= 0.f ? e0 : SLOPE * e0; w0 = __expf(e0);
            float e1 = elv.y + erv.y; e1 = e1 >= 0.f ? e1 : SLOPE * e1; w1 = __expf(e1);
            float e2 = elv.z + erv.z; e2 = e2 >= 0.f ? e2 : SLOPE * e2; w2 = __expf(e2);
        }
        int j = 0;
        for (; j + 8 <= cnt; j += 8) {
            unsigned short f0[8], f1[8], f2[8];
            float u0[8], u1[8], u2[8];
            #pragma unroll
            for (int q = 0; q < 8; ++q) {
                const int sj = __shfl(sv, j + q);
                const unsigned short* fp = &feat[(size_t)sj * NF + lane];
                f0[q] = fp[0]; f1[q] = fp[64]; f2[q] = fp[128];
                u0[q] = __shfl(w0, j + q);
                u1[q] = __shfl(w1, j + q);
                u2[q] = __shfl(w2, j + q);
            }
            #pragma unroll
            for (int q = 0; q < 8; ++q) {
                s0 += u0[q]; a0 += u0[q] * bf2f(f0[q]);
                s1 += u1[q]; a1 += u1[q] * bf2f(f1[q]);
                s2 += u2[q]; a2 += u2[q] * bf2f(f2[q]);
            }
        }
        for (; j < cnt; ++j) {
            const int sj = __shfl(sv, j);
            const float u0 = __shfl(w0, j);
            const float u1 = __shfl(w1, j);
            const float u2 = __shfl(w2, j);
            const unsigned short* fp = &feat[(size_t)sj * NF + lane];
            s0 += u0; a0 += u0 * bf2f(fp[0]);
            s1 += u1; a1 += u1 * bf2f(fp[64]);
            s2 += u2; a2 += u2 * bf2f(fp[128]);
        }
    }
    if (hi == lo) { s0 = 1.f; s1 = 1.f; s2 = 1.f; }
    float* op = &out[(size_t)d * NF];
    op[lane]       = a0 / s0;
    op[64 + lane]  = a1 / s1;
    op[128 + lane] = a2 / s2;
}

extern "C" void kernel_launch(void* const* d_in, const int* in_sizes, int n_in,
                              void* d_out, int out_size, void* d_ws, size_t ws_size,
                              hipStream_t stream) {
    const float* x      = (const float*)d_in[0];
    const float* W      = (const float*)d_in[1];
    const float* attn_l = (const float*)d_in[2];
    const float* attn_r = (const float*)d_in[3];
    const int*   src    = (const int*)d_in[4];
    const int*   dst    = (const int*)d_in[5];
    float* out = (float*)d_out;

    char* ws = (char*)d_ws;
    unsigned short* feat = (unsigned short*)ws;             // 76,800,000 B
    float* el4 = (float*)(ws + 76800000);                   // 3,200,000 B
    float* er4 = (float*)(ws + 80000000);                   //   800,000 B
    unsigned short* Wp = (unsigned short*)(ws + 80800000);  //   106,496 B
    int*   rp = (int*)(ws + 80906496);                      //   200,004 B

    prep_kernel<<<26 + 196, 256, 0, stream>>>(W, attn_l, attn_r, Wp, dst, rp);
    gemm_feat<<<GBLK, 512, 0, stream>>>(x, Wp, feat, el4, er4);
    gather_kernel<<<12500, 256, 0, stream>>>(feat, el4, er4, src, rp, out);
}

// Round 18
// 156.452 us; speedup vs baseline: 22.5851x; 22.5851x over previous
//
#include <hip/hip_runtime.h>
#include <hip/hip_bf16.h>

#define N_SRCN 200000
#define N_DSTN 50000
#define NEDGE 800000
#define KIN 256
#define NF 192        // H*OUT = 3*64
#define SLOPE 0.2f
#define TILES16 12500 // 16-row tiles
#define NWAVES 2048   // 256 blocks x 8 waves
#define SPAD 204      // staging row pitch (shorts): distinct bank offsets

typedef __attribute__((ext_vector_type(8))) short bf16x8;
typedef __attribute__((ext_vector_type(4))) float f32x4;

__device__ __forceinline__ unsigned short f2bf(float f) {
    union { float f; unsigned int u; } v; v.f = f;
    unsigned int u = v.u;
    return (unsigned short)((u + 0x7FFFu + ((u >> 16) & 1u)) >> 16);  // RNE
}
__device__ __forceinline__ float bf2f(unsigned short h) {
    union { unsigned int u; float f; } v; v.u = ((unsigned int)h) << 16;
    return v.f;
}
__device__ __forceinline__ unsigned int cvt2(float lo, float hi) {
    __hip_bfloat162 h = __float22bfloat162_rn(float2{lo, hi});
    union { __hip_bfloat162 h; unsigned int u; } c; c.h = h;
    return c.u;
}
__device__ __forceinline__ void gl_lds16(const void* g, void* l) {
    __builtin_amdgcn_global_load_lds(
        (const __attribute__((address_space(1))) unsigned int*)g,
        (__attribute__((address_space(3))) unsigned int*)l, 16, 0, 0);
}

// ---------------- merged prep: blocks 0-23 pack W; blocks 24+ build row_ptr --
// Wp[((ks*12 + nt)*64 + lane)*8 + j] = bf16(W[nt*16+(lane&15)][ks*32+(lane>>4)*8+j])
__global__ void prep_kernel(const float* __restrict__ W, unsigned short* __restrict__ Wp,
                            const int* __restrict__ dst, int* __restrict__ rp) {
    const int bid = blockIdx.x;
    if (bid < 24) {
        int tid = bid * 256 + threadIdx.x;
        if (tid >= 12 * 8 * 64) return;
        int lane = tid & 63;
        int g = tid >> 6;
        int nt = g % 12, ks = g / 12;
        int col = nt * 16 + (lane & 15);
        int k = ks * 32 + (lane >> 4) * 8;
        const float* wsrc = &W[col * KIN + k];
        unsigned short* o = &Wp[tid * 8];
        #pragma unroll
        for (int j = 0; j < 8; ++j) o[j] = f2bf(wsrc[j]);
    } else {
        int d = (bid - 24) * 256 + threadIdx.x;
        if (d > N_DSTN) return;
        int lo = 0, hi = NEDGE;
        while (lo < hi) {
            int mid = (lo + hi) >> 1;
            if (dst[mid] < d) lo = mid + 1; else hi = mid;
        }
        rp[d] = lo;
    }
}

// ---------------- GEMM: feat = x @ W^T (bf16 MFMA) + fused el/er -------------
// R10 structure (256 blocks x 512 thr, Wp in LDS once, barrier-free waves,
// 16-row tile per wave) + ONE change: feat stores go through a per-wave LDS
// transpose tile -> 6 fully-coalesced 1KB wave-stores per tile (48 full 128B
// lines, single writer) instead of 48 partial-line scattered stores.
__global__ void __launch_bounds__(512, 1)
gemm_feat(const float* __restrict__ x, const unsigned short* __restrict__ Wp,
          const float* __restrict__ attn_l, const float* __restrict__ attn_r,
          unsigned short* __restrict__ feat,
          float* __restrict__ el4, float* __restrict__ er4) {
    __shared__ unsigned short Bl[12 * 8 * 512];    // 96 KB, Wp fragment-major
    __shared__ unsigned short Stg[8][16][SPAD];    // 51 KB per-wave store staging
    const int t = threadIdx.x;
    const int wid = t >> 6, lane = t & 63;
    const int al = lane & 15, ah = lane >> 4;

    // ---- stage Wp -> LDS (12 sweeps x 8KB) ----
    #pragma unroll
    for (int i = 0; i < 12; ++i) {
        const int off = (i * 8 + wid) * 1024;
        gl_lds16((const char*)Wp + off + lane * 16, (char*)Bl + off);
    }
    asm volatile("s_waitcnt vmcnt(0)" ::: "memory");
    __syncthreads();
    // ---- no barriers after this point; Stg[wid] is wave-private ----

    float Al[12], Ar[12];
    #pragma unroll
    for (int nt = 0; nt < 12; ++nt) {
        Al[nt] = attn_l[nt * 16 + al];
        Ar[nt] = attn_r[nt * 16 + al];
    }

    const int gw = blockIdx.x * 8 + wid;
    for (int tile = gw; tile < TILES16; tile += NWAVES) {
        const int r0 = tile * 16;
        const float* xrow = &x[(size_t)(r0 + al) * KIN + ah * 8];

        f32x4 acc[12] = {};
        #pragma unroll
        for (int ks = 0; ks < 8; ++ks) {
            const float4 a0 = *(const float4*)&xrow[ks * 32];
            const float4 a1 = *(const float4*)&xrow[ks * 32 + 4];
            union { bf16x8 v; unsigned int u[4]; } av;
            av.u[0] = cvt2(a0.x, a0.y);
            av.u[1] = cvt2(a0.z, a0.w);
            av.u[2] = cvt2(a1.x, a1.y);
            av.u[3] = cvt2(a1.z, a1.w);
            #pragma unroll
            for (int nt = 0; nt < 12; ++nt) {
                const bf16x8 bv = *(const bf16x8*)&Bl[(ks * 12 + nt) * 512 + lane * 8];
                acc[nt] = __builtin_amdgcn_mfma_f32_16x16x32_bf16(av.v, bv, acc[nt], 0, 0, 0);
            }
        }

        // ---- epilogue 1a: acc -> LDS staging (C/D: col=nt*16+al, row=ah*4+e) --
        #pragma unroll
        for (int nt = 0; nt < 12; ++nt)
            #pragma unroll
            for (int e = 0; e < 4; ++e)
                Stg[wid][ah * 4 + e][nt * 16 + al] = f2bf(acc[nt][e]);

        // ---- epilogue 1b: LDS -> coalesced feat stores (6 x 1KB wave-store) --
        // chunk g = j*64+lane: row = g/24, col8 = g%24 (24 x 16B per 384B row)
        asm volatile("s_waitcnt lgkmcnt(0)" ::: "memory");
        __builtin_amdgcn_sched_barrier(0);
        #pragma unroll
        for (int j = 0; j < 6; ++j) {
            const int g = j * 64 + lane;
            const int row = g / 24, c8 = g % 24;
            const bf16x8 v = *(const bf16x8*)&Stg[wid][row][c8 * 8];
            *(bf16x8*)&feat[(size_t)(r0 + row) * NF + c8 * 8] = v;
        }

        // ---- epilogue 2: fused el/er (16-lane al-reduce per head) ----
        #pragma unroll
        for (int h = 0; h < 3; ++h) {
            #pragma unroll
            for (int e = 0; e < 4; ++e) {
                float sl = 0.f, sr = 0.f;
                #pragma unroll
                for (int q = 0; q < 4; ++q) {
                    const int nt = h * 4 + q;
                    sl += acc[nt][e] * Al[nt];
                    sr += acc[nt][e] * Ar[nt];
                }
                #pragma unroll
                for (int m = 1; m <= 8; m <<= 1) {
                    sl += __shfl_xor(sl, m);
                    sr += __shfl_xor(sr, m);
                }
                if (al == 0) {
                    const int row = r0 + ah * 4 + e;
                    el4[(size_t)row * 4 + h] = sl;
                    if (row < N_DSTN) er4[(size_t)row * 4 + h] = sr;
                }
            }
        }
    }
}

// ---------------- gather: edge softmax (no max shift) + weighted accumulate --
__launch_bounds__(256)
__global__ void gather_kernel(const unsigned short* __restrict__ feat,
                              const float* __restrict__ el4, const float* __restrict__ er4,
                              const int* __restrict__ src, const int* __restrict__ rp,
                              float* __restrict__ out) {
    const int lane = threadIdx.x & 63;
    const int d = (blockIdx.x * blockDim.x + threadIdx.x) >> 6;
    if (d >= N_DSTN) return;
    const int lo = rp[d], hi = rp[d + 1];
    const float4 erv = *(const float4*)&er4[(size_t)d * 4];

    float a0 = 0.f, a1 = 0.f, a2 = 0.f, s0 = 0.f, s1 = 0.f, s2 = 0.f;
    for (int base = lo; base < hi; base += 64) {
        const int cnt = min(64, hi - base);
        int sv = 0; float w0 = 0.f, w1 = 0.f, w2 = 0.f;
        if (lane < cnt) {
            sv = src[base + lane];
            const float4 elv = *(const float4*)&el4[(size_t)sv * 4];
            float e0 = elv.x + erv.x; e0 = e0 >= 0.f ? e0 : SLOPE * e0; w0 = __expf(e0);
            float e1 = elv.y + erv.y; e1 = e1 >= 0.f ? e1 : SLOPE * e1; w1 = __expf(e1);
            float e2 = elv.z + erv.z; e2 = e2 >= 0.f ? e2 : SLOPE * e2; w2 = __expf(e2);
        }
        int j = 0;
        for (; j + 8 <= cnt; j += 8) {
            unsigned short f0[8], f1[8], f2[8];
            float u0[8], u1[8], u2[8];
            #pragma unroll
            for (int q = 0; q < 8; ++q) {
                const int sj = __shfl(sv, j + q);
                const unsigned short* fp = &feat[(size_t)sj * NF + lane];
                f0[q] = fp[0]; f1[q] = fp[64]; f2[q] = fp[128];
                u0[q] = __shfl(w0, j + q);
                u1[q] = __shfl(w1, j + q);
                u2[q] = __shfl(w2, j + q);
            }
            #pragma unroll
            for (int q = 0; q < 8; ++q) {
                s0 += u0[q]; a0 += u0[q] * bf2f(f0[q]);
                s1 += u1[q]; a1 += u1[q] * bf2f(f1[q]);
                s2 += u2[q]; a2 += u2[q] * bf2f(f2[q]);
            }
        }
        for (; j < cnt; ++j) {
            const int sj = __shfl(sv, j);
            const float u0 = __shfl(w0, j);
            const float u1 = __shfl(w1, j);
            const float u2 = __shfl(w2, j);
            const unsigned short* fp = &feat[(size_t)sj * NF + lane];
            s0 += u0; a0 += u0 * bf2f(fp[0]);
            s1 += u1; a1 += u1 * bf2f(fp[64]);
            s2 += u2; a2 += u2 * bf2f(fp[128]);
        }
    }
    if (hi == lo) { s0 = 1.f; s1 = 1.f; s2 = 1.f; }
    float* op = &out[(size_t)d * NF];
    op[lane]       = a0 / s0;
    op[64 + lane]  = a1 / s1;
    op[128 + lane] = a2 / s2;
}

extern "C" void kernel_launch(void* const* d_in, const int* in_sizes, int n_in,
                              void* d_out, int out_size, void* d_ws, size_t ws_size,
                              hipStream_t stream) {
    const float* x      = (const float*)d_in[0];
    const float* W      = (const float*)d_in[1];
    const float* attn_l = (const float*)d_in[2];
    const float* attn_r = (const float*)d_in[3];
    const int*   src    = (const int*)d_in[4];
    const int*   dst    = (const int*)d_in[5];
    float* out = (float*)d_out;

    char* ws = (char*)d_ws;
    unsigned short* feat = (unsigned short*)ws;             // 76,800,000 B
    float* el4 = (float*)(ws + 76800000);                   // 3,200,000 B
    float* er4 = (float*)(ws + 80000000);                   //   800,000 B
    unsigned short* Wp = (unsigned short*)(ws + 80800000);  //    98,304 B
    int*   rp = (int*)(ws + 80898304);                      //   200,004 B

    prep_kernel<<<24 + 196, 256, 0, stream>>>(W, Wp, dst, rp);
    gemm_feat<<<256, 512, 0, stream>>>(x, Wp, attn_l, attn_r, feat, el4, er4);
    gather_kernel<<<12500, 256, 0, stream>>>(feat, el4, er4, src, rp, out);
}

// Round 19
// 152.565 us; speedup vs baseline: 23.1605x; 1.0255x over previous
//
#include <hip/hip_runtime.h>
#include <hip/hip_bf16.h>

#define N_SRCN 200000
#define N_DSTN 50000
#define NEDGE 800000
#define KIN 256
#define NF 192        // H*OUT = 3*64
#define SLOPE 0.2f
#define TILES16 12500 // 16-row tiles (12500*16 = 200000 exactly)
#define NWV 2048      // 256 blocks x 8 waves

typedef __attribute__((ext_vector_type(8))) short bf16x8;
typedef __attribute__((ext_vector_type(4))) float f32x4;

__device__ __forceinline__ unsigned short f2bf(float f) {
    union { float f; unsigned int u; } v; v.f = f;
    unsigned int u = v.u;
    return (unsigned short)((u + 0x7FFFu + ((u >> 16) & 1u)) >> 16);  // RNE
}
__device__ __forceinline__ float bf2f(unsigned short h) {
    union { unsigned int u; float f; } v; v.u = ((unsigned int)h) << 16;
    return v.f;
}
__device__ __forceinline__ unsigned int cvt2(float lo, float hi) {
    __hip_bfloat162 h = __float22bfloat162_rn(float2{lo, hi});
    union { __hip_bfloat162 h; unsigned int u; } c; c.h = h;
    return c.u;
}
__device__ __forceinline__ void gl_lds16(const void* g, void* l) {
    __builtin_amdgcn_global_load_lds(
        (const __attribute__((address_space(1))) unsigned int*)g,
        (__attribute__((address_space(3))) unsigned int*)l, 16, 0, 0);
}

// ---------------- merged prep: blocks 0-23 pack W; blocks 24+ build row_ptr --
// Wp[((ks*12 + nt)*64 + lane)*8 + j] = bf16(W[nt*16+(lane&15)][ks*32+(lane>>4)*8+j])
__global__ void prep_kernel(const float* __restrict__ W, unsigned short* __restrict__ Wp,
                            const int* __restrict__ dst, int* __restrict__ rp) {
    const int bid = blockIdx.x;
    if (bid < 24) {
        int tid = bid * 256 + threadIdx.x;
        if (tid >= 12 * 8 * 64) return;
        int lane = tid & 63;
        int g = tid >> 6;
        int nt = g % 12, ks = g / 12;
        int col = nt * 16 + (lane & 15);
        int k = ks * 32 + (lane >> 4) * 8;
        const float* wsrc = &W[col * KIN + k];
        unsigned short* o = &Wp[tid * 8];
        #pragma unroll
        for (int j = 0; j < 8; ++j) o[j] = f2bf(wsrc[j]);
    } else {
        int d = (bid - 24) * 256 + threadIdx.x;
        if (d > N_DSTN) return;
        int lo = 0, hi = NEDGE;
        while (lo < hi) {
            int mid = (lo + hi) >> 1;
            if (dst[mid] < d) lo = mid + 1; else hi = mid;
        }
        rp[d] = lo;
    }
}

// ---------------- GEMM: feat = x @ W^T (bf16 MFMA) + fused el/er -------------
// R10/R11 proven structure (Wp in 96KB LDS once, barrier-free waves, R11
// scatter-store epilogue which pre-warms L3 for gather) + DUAL-TILE ILP:
// each wave computes TWO 16-row tiles concurrently with fully-STATIC register
// names (R17 scratch lesson). Each B-fragment ds_read feeds 2 MFMAs (halves
// LDS traffic) and the two independent A-load chains double MLP per window.
// launch_bounds(512,1): VGPR cap 512, need ~150.
__global__ void __launch_bounds__(512, 1)
gemm_feat(const float* __restrict__ x, const unsigned short* __restrict__ Wp,
          const float* __restrict__ attn_l, const float* __restrict__ attn_r,
          unsigned short* __restrict__ feat,
          float* __restrict__ el4, float* __restrict__ er4) {
    __shared__ unsigned short Bl[12 * 8 * 512];    // 96 KB, Wp fragment-major
    const int t = threadIdx.x;
    const int wid = t >> 6, lane = t & 63;
    const int al = lane & 15, ah = lane >> 4;

    // ---- stage Wp -> LDS (12 sweeps x 8KB) ----
    #pragma unroll
    for (int i = 0; i < 12; ++i) {
        const int off = (i * 8 + wid) * 1024;
        gl_lds16((const char*)Wp + off + lane * 16, (char*)Bl + off);
    }
    asm volatile("s_waitcnt vmcnt(0)" ::: "memory");
    __syncthreads();
    // ---- no barriers after this point; waves fully independent ----

    float Al[12], Ar[12];
    #pragma unroll
    for (int nt = 0; nt < 12; ++nt) {
        Al[nt] = attn_l[nt * 16 + al];
        Ar[nt] = attn_r[nt * 16 + al];
    }

    const int gw = blockIdx.x * 8 + wid;           // 0..2047

    // epilogue helper (R11-verbatim pattern) as a macro over a static acc name
    #define EPILOGUE(ACC, R0)                                                  \
        {                                                                      \
            _Pragma("unroll")                                                  \
            for (int nt = 0; nt < 12; ++nt) {                                  \
                const int col = nt * 16 + al;                                  \
                _Pragma("unroll")                                              \
                for (int e = 0; e < 4; ++e) {                                  \
                    const int row = (R0) + ah * 4 + e;                         \
                    feat[(size_t)row * NF + col] = f2bf(ACC[nt][e]);           \
                }                                                              \
            }                                                                  \
            _Pragma("unroll")                                                  \
            for (int h = 0; h < 3; ++h) {                                      \
                _Pragma("unroll")                                              \
                for (int e = 0; e < 4; ++e) {                                  \
                    float sl = 0.f, sr = 0.f;                                  \
                    _Pragma("unroll")                                          \
                    for (int q = 0; q < 4; ++q) {                              \
                        const int nt = h * 4 + q;                              \
                        sl += ACC[nt][e] * Al[nt];                             \
                        sr += ACC[nt][e] * Ar[nt];                             \
                    }                                                          \
                    _Pragma("unroll")                                          \
                    for (int m = 1; m <= 8; m <<= 1) {                         \
                        sl += __shfl_xor(sl, m);                               \
                        sr += __shfl_xor(sr, m);                               \
                    }                                                          \
                    if (al == 0) {                                             \
                        const int row = (R0) + ah * 4 + e;                     \
                        el4[(size_t)row * 4 + h] = sl;                         \
                        if (row < N_DSTN) er4[(size_t)row * 4 + h] = sr;       \
                    }                                                          \
                }                                                              \
            }                                                                  \
        }

    // ---- main: 3 pairs of tiles per wave (all statically valid) ----
    for (int i = 0; i < 3; ++i) {
        const int t1 = gw + (2 * i) * NWV;
        const int t2 = t1 + NWV;                   // t2 <= 12287 < TILES16 ✓
        const int rA = t1 * 16, rB = t2 * 16;
        const float* xr1 = &x[(size_t)(rA + al) * KIN + ah * 8];
        const float* xr2 = &x[(size_t)(rB + al) * KIN + ah * 8];

        f32x4 accA[12] = {}, accB[12] = {};
        #pragma unroll
        for (int ks = 0; ks < 8; ++ks) {
            const float4 a10 = *(const float4*)&xr1[ks * 32];
            const float4 a11 = *(const float4*)&xr1[ks * 32 + 4];
            const float4 a20 = *(const float4*)&xr2[ks * 32];
            const float4 a21 = *(const float4*)&xr2[ks * 32 + 4];
            union { bf16x8 v; unsigned int u[4]; } av1, av2;
            av1.u[0] = cvt2(a10.x, a10.y);
            av1.u[1] = cvt2(a10.z, a10.w);
            av1.u[2] = cvt2(a11.x, a11.y);
            av1.u[3] = cvt2(a11.z, a11.w);
            av2.u[0] = cvt2(a20.x, a20.y);
            av2.u[1] = cvt2(a20.z, a20.w);
            av2.u[2] = cvt2(a21.x, a21.y);
            av2.u[3] = cvt2(a21.z, a21.w);
            #pragma unroll
            for (int nt = 0; nt < 12; ++nt) {
                const bf16x8 bv = *(const bf16x8*)&Bl[(ks * 12 + nt) * 512 + lane * 8];
                accA[nt] = __builtin_amdgcn_mfma_f32_16x16x32_bf16(av1.v, bv, accA[nt], 0, 0, 0);
                accB[nt] = __builtin_amdgcn_mfma_f32_16x16x32_bf16(av2.v, bv, accB[nt], 0, 0, 0);
            }
        }
        EPILOGUE(accA, rA)
        EPILOGUE(accB, rB)
    }

    // ---- tail: one extra tile for waves gw < 212 (tiles 12288..12499) ----
    if (gw < TILES16 - 6 * NWV) {
        const int tl = gw + 6 * NWV;
        const int r0 = tl * 16;
        const float* xr = &x[(size_t)(r0 + al) * KIN + ah * 8];
        f32x4 acc[12] = {};
        #pragma unroll
        for (int ks = 0; ks < 8; ++ks) {
            const float4 a0 = *(const float4*)&xr[ks * 32];
            const float4 a1 = *(const float4*)&xr[ks * 32 + 4];
            union { bf16x8 v; unsigned int u[4]; } av;
            av.u[0] = cvt2(a0.x, a0.y);
            av.u[1] = cvt2(a0.z, a0.w);
            av.u[2] = cvt2(a1.x, a1.y);
            av.u[3] = cvt2(a1.z, a1.w);
            #pragma unroll
            for (int nt = 0; nt < 12; ++nt) {
                const bf16x8 bv = *(const bf16x8*)&Bl[(ks * 12 + nt) * 512 + lane * 8];
                acc[nt] = __builtin_amdgcn_mfma_f32_16x16x32_bf16(av.v, bv, acc[nt], 0, 0, 0);
            }
        }
        EPILOGUE(acc, r0)
    }
    #undef EPILOGUE
}

// ---------------- gather: edge softmax (no max shift) + weighted accumulate --
__launch_bounds__(256)
__global__ void gather_kernel(const unsigned short* __restrict__ feat,
                              const float* __restrict__ el4, const float* __restrict__ er4,
                              const int* __restrict__ src, const int* __restrict__ rp,
                              float* __restrict__ out) {
    const int lane = threadIdx.x & 63;
    const int d = (blockIdx.x * blockDim.x + threadIdx.x) >> 6;
    if (d >= N_DSTN) return;
    const int lo = rp[d], hi = rp[d + 1];
    const float4 erv = *(const float4*)&er4[(size_t)d * 4];

    float a0 = 0.f, a1 = 0.f, a2 = 0.f, s0 = 0.f, s1 = 0.f, s2 = 0.f;
    for (int base = lo; base < hi; base += 64) {
        const int cnt = min(64, hi - base);
        int sv = 0; float w0 = 0.f, w1 = 0.f, w2 = 0.f;
        if (lane < cnt) {
            sv = src[base + lane];
            const float4 elv = *(const float4*)&el4[(size_t)sv * 4];
            float e0 = elv.x + erv.x; e0 = e0 >= 0.f ? e0 : SLOPE * e0; w0 = __expf(e0);
            float e1 = elv.y + erv.y; e1 = e1 >= 0.f ? e1 : SLOPE * e1; w1 = __expf(e1);
            float e2 = elv.z + erv.z; e2 = e2 >= 0.f ? e2 : SLOPE * e2; w2 = __expf(e2);
        }
        int j = 0;
        for (; j + 8 <= cnt; j += 8) {
            unsigned short f0[8], f1[8], f2[8];
            float u0[8], u1[8], u2[8];
            #pragma unroll
            for (int q = 0; q < 8; ++q) {
                const int sj = __shfl(sv, j + q);
                const unsigned short* fp = &feat[(size_t)sj * NF + lane];
                f0[q] = fp[0]; f1[q] = fp[64]; f2[q] = fp[128];
                u0[q] = __shfl(w0, j + q);
                u1[q] = __shfl(w1, j + q);
                u2[q] = __shfl(w2, j + q);
            }
            #pragma unroll
            for (int q = 0; q < 8; ++q) {
                s0 += u0[q]; a0 += u0[q] * bf2f(f0[q]);
                s1 += u1[q]; a1 += u1[q] * bf2f(f1[q]);
                s2 += u2[q]; a2 += u2[q] * bf2f(f2[q]);
            }
        }
        for (; j < cnt; ++j) {
            const int sj = __shfl(sv, j);
            const float u0 = __shfl(w0, j);
            const float u1 = __shfl(w1, j);
            const float u2 = __shfl(w2, j);
            const unsigned short* fp = &feat[(size_t)sj * NF + lane];
            s0 += u0; a0 += u0 * bf2f(fp[0]);
            s1 += u1; a1 += u1 * bf2f(fp[64]);
            s2 += u2; a2 += u2 * bf2f(fp[128]);
        }
    }
    if (hi == lo) { s0 = 1.f; s1 = 1.f; s2 = 1.f; }
    float* op = &out[(size_t)d * NF];
    op[lane]       = a0 / s0;
    op[64 + lane]  = a1 / s1;
    op[128 + lane] = a2 / s2;
}

extern "C" void kernel_launch(void* const* d_in, const int* in_sizes, int n_in,
                              void* d_out, int out_size, void* d_ws, size_t ws_size,
                              hipStream_t stream) {
    const float* x      = (const float*)d_in[0];
    const float* W      = (const float*)d_in[1];
    const float* attn_l = (const float*)d_in[2];
    const float* attn_r = (const float*)d_in[3];
    const int*   src    = (const int*)d_in[4];
    const int*   dst    = (const int*)d_in[5];
    float* out = (float*)d_out;

    char* ws = (char*)d_ws;
    unsigned short* feat = (unsigned short*)ws;             // 76,800,000 B
    float* el4 = (float*)(ws + 76800000);                   // 3,200,000 B
    float* er4 = (float*)(ws + 80000000);                   //   800,000 B
    unsigned short* Wp = (unsigned short*)(ws + 80800000);  //    98,304 B
    int*   rp = (int*)(ws + 80898304);                      //   200,004 B

    prep_kernel<<<24 + 196, 256, 0, stream>>>(W, Wp, dst, rp);
    gemm_feat<<<256, 512, 0, stream>>>(x, Wp, attn_l, attn_r, feat, el4, er4);
    gather_kernel<<<12500, 256, 0, stream>>>(feat, el4, er4, src, rp, out);
}